// Round 19
// baseline (153.048 us; speedup 1.0000x reference)
//
#include <hip/hip_runtime.h>
#include <cstdint>

// ---------- types ----------
typedef __bf16 bf16x8 __attribute__((ext_vector_type(8)));
typedef float f32x4 __attribute__((ext_vector_type(4)));
typedef float f32x16 __attribute__((ext_vector_type(16)));
typedef unsigned short u16x8 __attribute__((ext_vector_type(8)));
typedef unsigned short u16x4 __attribute__((ext_vector_type(4)));
typedef unsigned int uint32x4 __attribute__((ext_vector_type(4)));
typedef unsigned int uint_g __attribute__((address_space(1)));
typedef unsigned int uint_l __attribute__((address_space(3)));

#define MFMA16(a, b, c) __builtin_amdgcn_mfma_f32_16x16x32_bf16(a, b, c, 0, 0, 0)
#define MFMA32(a, b, c) __builtin_amdgcn_mfma_f32_32x32x16_bf16(a, b, c, 0, 0, 0)

static __device__ __forceinline__ unsigned short f2bf(float f) {
    unsigned u = __builtin_bit_cast(unsigned, f);
    u += 0x7FFFu + ((u >> 16) & 1u);
    return (unsigned short)(u >> 16);
}
static __device__ __forceinline__ float bf2f(unsigned short h) {
    unsigned u = ((unsigned)h) << 16;
    return __builtin_bit_cast(float, u);
}
static __device__ __forceinline__ void gload16(const unsigned short* g, unsigned short* lds) {
    __builtin_amdgcn_global_load_lds((uint_g*)g, (uint_l*)lds, 16, 0, 0);
}
static __device__ __forceinline__ unsigned cvt_pk_bf16(float a, float b) {
    unsigned r;
    asm("v_cvt_pk_bf16_f32 %0, %1, %2" : "=v"(r) : "v"(a), "v"(b));
    return r;
}

// ---------- constants ----------
// B=2, S=2048, DIM=1024, H=16, D=64
#define SB 2048
#define NROWS 4096       // B*S
#define DIMM 1024
#define NH 16
#define HD 64
#define QSCALE 0.18033688011112043f  // 0.125 * log2(e): folded into q-weights in convert

// ---------- fused f32 -> bf16 convert: hidden(4M) || qkv_w(3M) || out_w(1M) octets ----------
// q-rows of qkv_w (first 131072 octets of s1) are pre-scaled by QSCALE so attention's
// exp2-domain softmax scale is free (q = (QSC*W)x + QSC*b; RoPE commutes with scalars).
__global__ __launch_bounds__(256) void k_convert(const float* __restrict__ s0,
                                                 const float* __restrict__ s1,
                                                 const float* __restrict__ s2,
                                                 unsigned short* __restrict__ dst) {
    int base = blockIdx.x * 256 + threadIdx.x;  // grid 1024 -> 262144 threads
#pragma unroll
    for (int v = 0; v < 4; ++v) {
        int i = base + v * 262144;
        const float* src;
        int rel;
        float sc = 1.0f;
        if (i < 524288) { src = s0; rel = i; }
        else if (i < 917504) {
            src = s1; rel = i - 524288;
            if (rel < 131072) sc = QSCALE;   // q-weight rows
        }
        else { src = s2; rel = i - 917504; }
        const float4* p = (const float4*)src + (size_t)rel * 2;
        float4 a = p[0], bq = p[1];
        u16x8 o;
        o[0] = f2bf(a.x * sc);  o[1] = f2bf(a.y * sc);
        o[2] = f2bf(a.z * sc);  o[3] = f2bf(a.w * sc);
        o[4] = f2bf(bq.x * sc); o[5] = f2bf(bq.y * sc);
        o[6] = f2bf(bq.z * sc); o[7] = f2bf(bq.w * sc);
        *((u16x8*)dst + i) = o;
    }
}

// ---------- RoPE on head 0 of q and k, vectorized: 256x256, 8 elems/thread ----------
__global__ __launch_bounds__(256) void k_rope(unsigned short* __restrict__ qk,
                                              const float* __restrict__ cosp,
                                              const float* __restrict__ sinp) {
    int gid = blockIdx.x * 256 + threadIdx.x;   // grid 256 -> 65536 threads
    int row = gid >> 4;
    int seg = gid & 15;
    int which = seg >> 3;
    int e0 = (seg & 7) * 8;
    unsigned short* base = qk + (size_t)row * 2048 + which * 1024 + e0;
    u16x8 v = *(u16x8*)base;
    const float* cb = cosp + (size_t)row * 64 + e0;
    const float* sb = sinp + (size_t)row * 64 + e0;
    float4 c0 = *(const float4*)cb, c1 = *(const float4*)(cb + 4);
    float4 s0 = *(const float4*)sb, s1 = *(const float4*)(sb + 4);
    float c[8] = {c0.x, c0.y, c0.z, c0.w, c1.x, c1.y, c1.z, c1.w};
    float s[8] = {s0.x, s0.y, s0.z, s0.w, s1.x, s1.y, s1.z, s1.w};
    u16x8 o;
#pragma unroll
    for (int p = 0; p < 4; ++p) {
        float x0 = bf2f(v[2 * p]);
        float x1 = bf2f(v[2 * p + 1]);
        o[2 * p]     = f2bf(x0 * c[2 * p] - x1 * s[2 * p]);
        o[2 * p + 1] = f2bf(x1 * c[2 * p + 1] + x0 * s[2 * p + 1]);
    }
    *(u16x8*)base = o;
}

// ---------- NT GEMM: C[M,N] = A[M,K] * B[N,K]^T + bias ----------
// r19: attn-style asymmetric prefetch (the round-8 trick, applied to GEMM).
// A staged to LDS (double-buffered, T2 XOR-swizzled, gload_lds); B fragments loaded
// DIRECT to registers one iteration ahead (per-lane b128 at the fragment address — B
// never touches LDS). Per iter t: stage A(t+1) | load B(t+1)->regs | compute(t) |
// vmcnt(8) [drains exactly the A-stage (oldest; 4 or 2 loads), keeps all 8 B-loads in
// flight across the barrier] | raw s_barrier. A-latency hides under a full tile's MFMA;
// B-latency hides under a full iteration; Bs LDS + 8 ds_reads + 1 barrier/iter deleted.
// [r10 dbuf failed because both operands in LDS force vmcnt(0) at the barrier.]
// + T1 XCD-chunked grid swizzle (bijective; chunk grid (NX/CX)*(NY/CY) == 8).
// MODE 0: qkv epilogue -> q,k bf16 (q-cols bias scaled by QSCALE); v -> fragment-tiled.
// MODE 1: f32 epilogue -> outF[M][N]. K must be 1024 (16 iters, unrolled pairwise).
#define GEMM_BODY(T, BC, BN, DOSTAGE)                                                    \
  {                                                                                      \
    if (DOSTAGE) {                                                                       \
      stageA(((T) + 1) & 1, ((T) + 1) * 64);                                             \
      _Pragma("unroll") for (int ni = 0; ni < 4; ++ni)                                   \
        _Pragma("unroll") for (int s = 0; s < 2; ++s)                                    \
          BN[ni][s] = *(const bf16x8*)(Bf + (size_t)ni * 16 * K + ((T) + 1) * 64 + s * 32); \
    }                                                                                    \
    const unsigned short* Ab = &As[(T) & 1][0];                                          \
    bf16x8 af[MI][2];                                                                    \
    _Pragma("unroll") for (int mi = 0; mi < MI; ++mi)                                    \
      _Pragma("unroll") for (int s = 0; s < 2; ++s)                                      \
        af[mi][s] = *(const bf16x8*)&Ab[(wm * (BM / 2) + mi * 16 + lr) * 64 +            \
                                        ((s * 32 + lg * 8) ^ rsw)];                      \
    __builtin_amdgcn_s_setprio(1);                                                       \
    _Pragma("unroll") for (int mi = 0; mi < MI; ++mi)                                    \
      _Pragma("unroll") for (int ni = 0; ni < 4; ++ni)                                   \
        _Pragma("unroll") for (int s = 0; s < 2; ++s)                                    \
          acc[mi][ni] = MFMA16(af[mi][s], BC[ni][s], acc[mi][ni]);                       \
    __builtin_amdgcn_s_setprio(0);                                                       \
    if (DOSTAGE) {                                                                       \
      asm volatile("s_waitcnt vmcnt(8)" ::: "memory");                                   \
      __builtin_amdgcn_s_barrier();                                                      \
    }                                                                                    \
  }

template <int MODE, int BM, int NX, int CX, int CY>
__global__ __launch_bounds__(256) void k_gemm_nt(
    const unsigned short* __restrict__ A, const unsigned short* __restrict__ B,
    const float* __restrict__ bias, unsigned short* __restrict__ outQK,
    unsigned short* __restrict__ outVg, float* __restrict__ outF, int M, int N, int K) {
    constexpr int MI = BM / 32;          // acc rows per wave / 16
    __shared__ __align__(16) unsigned short As[2][BM * 64];
    const int tid = threadIdx.x;
    const int w = tid >> 6, l = tid & 63, lr = l & 15, lg = l >> 4;
    const int wm = w >> 1, wn = w & 1;

    // XCD-chunked block swizzle (bijective; chunk grid (NX/CX) x (NY/CY) == 8)
    const int flat = blockIdx.x;
    const int xcd = flat & 7, within = flat >> 3;
    const int bx = (xcd % (NX / CX)) * CX + within % CX;
    const int by = (xcd / (NX / CX)) * CY + within / CX;
    const int m0 = by * BM, n0 = bx * 128;

    f32x4 acc[MI][4];
    f32x4 zero4 = {0.f, 0.f, 0.f, 0.f};
#pragma unroll
    for (int i = 0; i < MI; ++i)
#pragma unroll
        for (int j = 0; j < 4; ++j) acc[i][j] = zero4;

    const int trow = tid >> 3;
    const int tkb = (tid & 7) ^ ((tid >> 3) & 7);   // inverse-swizzled A source chunk
    const unsigned short* Ag = A + (size_t)(m0 + trow) * K + tkb * 8;
    const int rsw = (lr & 7) << 3;                  // A read-side swizzle (u16 units)
    // B fragment base: row = n0 + wn*64 + lr (+16*ni), col = kt + s*32 + lg*8
    const unsigned short* Bf = B + (size_t)(n0 + wn * 64 + lr) * K + lg * 8;

    auto stageA = [&](int bufi, int kt) {
#pragma unroll
        for (int i = 0; i < BM / 32; ++i)
            gload16(Ag + (size_t)i * 32 * K + kt,
                    (unsigned short*)((char*)&As[bufi][0] + i * 4096 + w * 1024));
    };

    bf16x8 bA[4][2], bB[4][2];

    // prologue: stage A(0); load B(0) regs; drain A only; barrier
    stageA(0, 0);
#pragma unroll
    for (int ni = 0; ni < 4; ++ni)
#pragma unroll
        for (int s = 0; s < 2; ++s)
            bA[ni][s] = *(const bf16x8*)(Bf + (size_t)ni * 16 * K + s * 32);
    asm volatile("s_waitcnt vmcnt(8)" ::: "memory");
    __builtin_amdgcn_s_barrier();

    // 16 K-iters: pairs 0..13, body 14 staged (loads 15), body 15 tail
    for (int tt = 0; tt < 7; ++tt) {
        const int t = 2 * tt;
        GEMM_BODY(t,     bA, bB, true)
        GEMM_BODY(t + 1, bB, bA, true)
    }
    GEMM_BODY(14, bA, bB, true)
    GEMM_BODY(15, bB, bA, false)

#pragma unroll
    for (int mi = 0; mi < MI; ++mi)
#pragma unroll
        for (int ni = 0; ni < 4; ++ni) {
            int gc = n0 + wn * 64 + ni * 16 + lr;
            int gr0 = m0 + wm * (BM / 2) + mi * 16 + lg * 4;
            float bv = bias[gc];
            if (MODE == 0 && gc < 1024) bv *= QSCALE;   // match pre-scaled q-weights
            f32x4 v = acc[mi][ni];
            if (MODE == 0) {
                if (gc < 2048) {
#pragma unroll
                    for (int r = 0; r < 4; ++r)
                        outQK[(size_t)(gr0 + r) * 2048 + gc] = f2bf(v[r] + bv);
                } else {
                    // V -> fragment-tiled layout (see k_attn V loads):
                    // addr(u16) = ((bh*32+T)*8 + db*4 + ks)*512 + (hi8*32+lq)*8 + j
                    int e = gc - 2048;
                    int hh = e >> 6, d = e & 63;
                    int bb = gr0 >> 11, s = gr0 & 2047;  // s multiple of 4
                    int bh = bb * NH + hh;
                    int T = s >> 6, w64 = s & 63;
                    int ks = w64 >> 4, hi8 = (w64 >> 3) & 1, j0 = w64 & 7;  // j0 in {0,4}
                    int db = d >> 5, lqv = d & 31;
                    u16x4 pk;
#pragma unroll
                    for (int r = 0; r < 4; ++r) pk[r] = f2bf(v[r] + bv);
                    size_t off = ((size_t)((bh * 32 + T) * 8 + db * 4 + ks)) * 512 +
                                 (hi8 * 32 + lqv) * 8 + j0;
                    *(u16x4*)&outVg[off] = pk;
                }
            } else {
#pragma unroll
                for (int r = 0; r < 4; ++r)
                    outF[(size_t)(gr0 + r) * N + gc] = v[r] + bv;
            }
        }
}

// ---------- flash attention: full-kv per block, software-pipelined (round-14 form) ----------
// grid 1024 (XCD-swizzled), 128 threads = 2 waves, 32 q-rows/wave, 32 kv-tiles.
// Body t: stage K_{t+2} | load V_{t+1} | QK_{t+1} (MFMA) | PV_t + l-MFMA | exp2 | pack
// | vmcnt(8) (drain own K-stage, keep V in flight) | raw s_barrier.
// Row-sum l on the MATRIX pipe: lacc = MFMA32(pa, ones). Q pre-scaled by QSCALE.
// [r15: barrier-free 1-wave variant was 53 µs vs this form's 49.5 — structural floor.]
#define ATTN_BODY(T, PA, VA0, VA1, PB, VB0, VB1, DOSTAGE)                                \
  {                                                                                      \
    if (DOSTAGE) stageK((T) & 1, (T) + 2);                                               \
    const unsigned short* vtbN = vgb + (size_t)((T) + 1) * 4096;                         \
    _Pragma("unroll") for (int ks = 0; ks < 4; ++ks)                                     \
        VB0[ks] = *(const bf16x8*)&vtbN[(size_t)ks * 512 + l * 8];                       \
    _Pragma("unroll") for (int ks = 0; ks < 4; ++ks)                                     \
        VB1[ks] = *(const bf16x8*)&vtbN[(size_t)(4 + ks) * 512 + l * 8];                 \
    const char* Kb = (const char*)Ks[((T) + 1) & 1];                                     \
    f32x16 s0, s1;                                                                       \
    __builtin_amdgcn_s_setprio(1);                                                       \
    _Pragma("unroll") for (int ds = 0; ds < 4; ++ds) {                                   \
        bf16x8 kf0 = *(const bf16x8*)(Kb + lq * 128 + ((ds * 32 + hi * 16) ^ swz));      \
        bf16x8 kf1 = *(const bf16x8*)(Kb + (32 + lq) * 128 + ((ds * 32 + hi * 16) ^ swz)); \
        s0 = (ds == 0) ? MFMA32(kf0, qf[0], z16) : MFMA32(kf0, qf[ds], s0);              \
        s1 = (ds == 0) ? MFMA32(kf1, qf[0], z16) : MFMA32(kf1, qf[ds], s1);              \
    }                                                                                    \
    _Pragma("unroll") for (int ks = 0; ks < 4; ++ks) {                                   \
        oacc[0] = MFMA32(PA[ks], VA0[ks], oacc[0]);                                      \
        oacc[1] = MFMA32(PA[ks], VA1[ks], oacc[1]);                                      \
        lacc    = MFMA32(PA[ks], vones,   lacc);                                         \
    }                                                                                    \
    __builtin_amdgcn_s_setprio(0);                                                       \
    _Pragma("unroll") for (int r = 0; r < 16; ++r) {                                     \
        s0[r] = __builtin_amdgcn_exp2f(s0[r]);                                           \
        s1[r] = __builtin_amdgcn_exp2f(s1[r]);                                           \
    }                                                                                    \
    _Pragma("unroll") for (int ks = 0; ks < 4; ++ks) {                                   \
        const int k2 = ks & 1;                                                           \
        f32x16& sb = (ks < 2) ? s0 : s1;                                                 \
        unsigned XA = cvt_pk_bf16(sb[8 * k2 + 0], sb[8 * k2 + 1]);                       \
        unsigned YA = cvt_pk_bf16(sb[8 * k2 + 2], sb[8 * k2 + 3]);                       \
        unsigned XB = cvt_pk_bf16(sb[8 * k2 + 4], sb[8 * k2 + 5]);                       \
        unsigned YB = cvt_pk_bf16(sb[8 * k2 + 6], sb[8 * k2 + 7]);                       \
        asm("v_permlane32_swap_b32 %0, %1" : "+v"(XA), "+v"(XB));                        \
        asm("v_permlane32_swap_b32 %0, %1" : "+v"(YA), "+v"(YB));                        \
        uint32x4 pw;                                                                     \
        pw[0] = XA; pw[1] = YA; pw[2] = XB; pw[3] = YB;                                  \
        PB[ks] = __builtin_bit_cast(bf16x8, pw);                                         \
    }                                                                                    \
    if (DOSTAGE) {                                                                      \
        asm volatile("s_waitcnt vmcnt(8)" ::: "memory");                                 \
        __builtin_amdgcn_s_barrier();                                                    \
    }                                                                                    \
  }

__global__ __launch_bounds__(128, 2) void k_attn(const unsigned short* __restrict__ qk,
                                                 const unsigned short* __restrict__ vg,
                                                 unsigned short* __restrict__ ao) {
    const int raw = blockIdx.x;
    const int bid = (raw & 7) * 128 + (raw >> 3);  // XCD swizzle: 4 bh-groups per XCD
    const int qt = bid & 31, bh = bid >> 5, b = bh >> 4, h = bh & 15;
    const int tid = threadIdx.x, w = tid >> 6, l = tid & 63;
    const int lq = l & 31, hi = l >> 5;

    __shared__ __align__(16) unsigned short Ks[2][4096];  // [kv 64][d 64], XOR-swizzled cols

    const size_t rowbase = (size_t)b * SB;
    const int qrow = qt * 64 + w * 32 + lq;

    // Q B-fragments (pre-scaled in convert): qf[ds] = Q[qrow][16ds + 8hi .. +8)
    bf16x8 qf[4];
#pragma unroll
    for (int ds = 0; ds < 4; ++ds)
        qf[ds] = *(const bf16x8*)&qk[(rowbase + qrow) * 2048 + h * 64 + ds * 16 + hi * 8];

    // ones B-fragment for the l-MFMA (every element 1.0bf16)
    u16x8 onesu;
#pragma unroll
    for (int j = 0; j < 8; ++j) onesu[j] = 0x3F80;
    const bf16x8 vones = __builtin_bit_cast(bf16x8, onesu);

    // K staging: linear LDS dest, inverse-swizzled global source (rule 21)
    const char* ksrc[4];
#pragma unroll
    for (int j = 0; j < 4; ++j) {
        int Lb = (j * 2 + w) * 1024 + l * 16;
        int r = Lb >> 7, c = Lb & 127;
        int cs = c ^ ((r & 7) << 4);
        ksrc[j] = (const char*)qk + ((size_t)(rowbase + r) * 2048 + 1024 + h * 64) * 2 + cs;
    }
    auto stageK = [&](int bufi, int tg) {
#pragma unroll
        for (int j = 0; j < 4; ++j)
            gload16((const unsigned short*)(ksrc[j] + (size_t)tg * 262144),
                    Ks[bufi] + (j * 2 + w) * 512);
    };

    const unsigned short* vgb = vg + (size_t)bh * 131072;  // 32 tiles * 8 frags * 512

    f32x16 z16 = {0.f, 0.f, 0.f, 0.f, 0.f, 0.f, 0.f, 0.f,
                  0.f, 0.f, 0.f, 0.f, 0.f, 0.f, 0.f, 0.f};
    f32x16 oacc[2];
    oacc[0] = z16;
    oacc[1] = z16;
    f32x16 lacc = z16;
    const int swz = (l & 7) << 4;

    bf16x8 vfA0[4], vfA1[4], vfB0[4], vfB1[4];
    bf16x8 paA[4], paB[4];

    // ---- prologue: K_0 staged+drained; K_1 in flight; V_0, QK_0, pack paA ----
    stageK(0, 0);
    __syncthreads();  // full drain: K_0 ready for all waves
    stageK(1, 1);
#pragma unroll
    for (int ks = 0; ks < 4; ++ks)
        vfA0[ks] = *(const bf16x8*)&vgb[(size_t)ks * 512 + l * 8];
#pragma unroll
    for (int ks = 0; ks < 4; ++ks)
        vfA1[ks] = *(const bf16x8*)&vgb[(size_t)(4 + ks) * 512 + l * 8];
    {
        const char* Kb = (const char*)Ks[0];
        f32x16 s0, s1;
#pragma unroll
        for (int ds = 0; ds < 4; ++ds) {
            bf16x8 kf0 = *(const bf16x8*)(Kb + lq * 128 + ((ds * 32 + hi * 16) ^ swz));
            bf16x8 kf1 = *(const bf16x8*)(Kb + (32 + lq) * 128 + ((ds * 32 + hi * 16) ^ swz));
            s0 = (ds == 0) ? MFMA32(kf0, qf[0], z16) : MFMA32(kf0, qf[ds], s0);
            s1 = (ds == 0) ? MFMA32(kf1, qf[0], z16) : MFMA32(kf1, qf[ds], s1);
        }
#pragma unroll
        for (int r = 0; r < 16; ++r) {
            s0[r] = __builtin_amdgcn_exp2f(s0[r]);
            s1[r] = __builtin_amdgcn_exp2f(s1[r]);
        }
#pragma unroll
        for (int ks = 0; ks < 4; ++ks) {
            const int k2 = ks & 1;
            f32x16& sb = (ks < 2) ? s0 : s1;
            unsigned XA = cvt_pk_bf16(sb[8 * k2 + 0], sb[8 * k2 + 1]);
            unsigned YA = cvt_pk_bf16(sb[8 * k2 + 2], sb[8 * k2 + 3]);
            unsigned XB = cvt_pk_bf16(sb[8 * k2 + 4], sb[8 * k2 + 5]);
            unsigned YB = cvt_pk_bf16(sb[8 * k2 + 6], sb[8 * k2 + 7]);
            asm("v_permlane32_swap_b32 %0, %1" : "+v"(XA), "+v"(XB));
            asm("v_permlane32_swap_b32 %0, %1" : "+v"(YA), "+v"(YB));
            uint32x4 pw;
            pw[0] = XA; pw[1] = YA; pw[2] = XB; pw[3] = YB;
            paA[ks] = __builtin_bit_cast(bf16x8, pw);
        }
    }
    asm volatile("s_waitcnt vmcnt(8)" ::: "memory");  // drain K_1 stage; keep V_0 loads
    __builtin_amdgcn_s_barrier();

    // ---- main loop: bodies t = 0..29 paired (A->B, B->A), tail t = 30 ----
    for (int tt = 0; tt < 15; ++tt) {
        const int t = 2 * tt;
        ATTN_BODY(t,     paA, vfA0, vfA1, paB, vfB0, vfB1, true)
        ATTN_BODY(t + 1, paB, vfB0, vfB1, paA, vfA0, vfA1, true)
    }
    ATTN_BODY(30, paA, vfA0, vfA1, paB, vfB0, vfB1, false)
    // tail PV_31 (+ l accumulation)
    __builtin_amdgcn_s_setprio(1);
#pragma unroll
    for (int ks = 0; ks < 4; ++ks) {
        oacc[0] = MFMA32(paB[ks], vfB0[ks], oacc[0]);
        oacc[1] = MFMA32(paB[ks], vfB1[ks], oacc[1]);
        lacc    = MFMA32(paB[ks], vones,   lacc);
    }
    __builtin_amdgcn_s_setprio(0);

    // epilogue: per-lane normalization via lacc (no cross-lane ops)
#pragma unroll
    for (int r = 0; r < 16; ++r) {
        float inv = __builtin_amdgcn_rcpf(lacc[r]);
        int qv = (r & 3) + 8 * (r >> 2) + 4 * hi;
        int qg = qt * 64 + w * 32 + qv;
        ao[(rowbase + qg) * DIMM + h * 64 + lq] = f2bf(oacc[0][r] * inv);
        ao[(rowbase + qg) * DIMM + h * 64 + 32 + lq] = f2bf(oacc[1][r] * inv);
    }
}

// ---------- launch ----------
extern "C" void kernel_launch(void* const* d_in, const int* in_sizes, int n_in,
                              void* d_out, int out_size, void* d_ws, size_t ws_size,
                              hipStream_t stream) {
    const float* hidden = (const float*)d_in[0];
    const float* cosp   = (const float*)d_in[1];
    const float* sinp   = (const float*)d_in[2];
    const float* qkv_w  = (const float*)d_in[3];
    const float* qkv_b  = (const float*)d_in[4];
    const float* out_w  = (const float*)d_in[5];
    const float* out_b  = (const float*)d_in[6];
    float* out = (float*)d_out;

    // ws layout (40 MB):
    unsigned short* hbf   = (unsigned short*)d_ws;                 // [0, 8M)   4M elems
    unsigned short* wqkv  = hbf + (size_t)NROWS * DIMM;            // [8, 14M)  3M elems
    unsigned short* wout  = wqkv + (size_t)3072 * DIMM;            // [14, 16M) 1M elems
    unsigned short* qkbuf = wout + (size_t)DIMM * DIMM;            // [16, 32M) q,k
    unsigned short* vgbuf = qkbuf + (size_t)NROWS * 2048;          // [32, 40M) V fragment-tiled
    unsigned short* aobuf = hbf;                                   // alias: hbf dead after GEMM1

    k_convert<<<1024, 256, 0, stream>>>(hidden, qkv_w, out_w, hbf);
    // GEMM1: NX=24 x NY=32 blocks; XCD chunks 12x8 (2x4 chunk grid = 8 XCDs)
    k_gemm_nt<0, 128, 24, 12, 8><<<768, 256, 0, stream>>>(hbf, wqkv, qkv_b, qkbuf, vgbuf,
                                                          nullptr, NROWS, 3072, DIMM);
    k_rope<<<256, 256, 0, stream>>>(qkbuf, cosp, sinp);
    k_attn<<<1024, 128, 0, stream>>>(qkbuf, vgbuf, aobuf);
    // GEMM2: NX=8 x NY=64 blocks; XCD chunks 8x8 (1x8 chunk grid = 8 XCDs)
    k_gemm_nt<1, 64, 8, 8, 8><<<512, 256, 0, stream>>>(aobuf, wout, out_b, nullptr, nullptr,
                                                       out, NROWS, DIMM, DIMM);
}

// Round 20
// 112.777 us; speedup vs baseline: 1.3571x; 1.3571x over previous
//
#include <hip/hip_runtime.h>
#include <cstdint>

// ---------- types ----------
typedef __bf16 bf16x8 __attribute__((ext_vector_type(8)));
typedef float f32x4 __attribute__((ext_vector_type(4)));
typedef float f32x16 __attribute__((ext_vector_type(16)));
typedef unsigned short u16x8 __attribute__((ext_vector_type(8)));
typedef unsigned short u16x4 __attribute__((ext_vector_type(4)));
typedef unsigned int uint32x4 __attribute__((ext_vector_type(4)));
typedef unsigned int uint_g __attribute__((address_space(1)));
typedef unsigned int uint_l __attribute__((address_space(3)));

#define MFMA16(a, b, c) __builtin_amdgcn_mfma_f32_16x16x32_bf16(a, b, c, 0, 0, 0)
#define MFMA32(a, b, c) __builtin_amdgcn_mfma_f32_32x32x16_bf16(a, b, c, 0, 0, 0)

static __device__ __forceinline__ unsigned short f2bf(float f) {
    unsigned u = __builtin_bit_cast(unsigned, f);
    u += 0x7FFFu + ((u >> 16) & 1u);
    return (unsigned short)(u >> 16);
}
static __device__ __forceinline__ float bf2f(unsigned short h) {
    unsigned u = ((unsigned)h) << 16;
    return __builtin_bit_cast(float, u);
}
static __device__ __forceinline__ void gload16(const unsigned short* g, unsigned short* lds) {
    __builtin_amdgcn_global_load_lds((uint_g*)g, (uint_l*)lds, 16, 0, 0);
}
static __device__ __forceinline__ unsigned cvt_pk_bf16(float a, float b) {
    unsigned r;
    asm("v_cvt_pk_bf16_f32 %0, %1, %2" : "=v"(r) : "v"(a), "v"(b));
    return r;
}

// ---------- constants ----------
// B=2, S=2048, DIM=1024, H=16, D=64
#define SB 2048
#define NROWS 4096       // B*S
#define DIMM 1024
#define NH 16
#define HD 64
#define QSCALE 0.18033688011112043f  // 0.125 * log2(e): folded into q-weights in convert

// ---------- fused f32 -> bf16 convert: hidden(4M) || qkv_w(3M) || out_w(1M) octets ----------
// q-rows of qkv_w (first 131072 octets of s1) are pre-scaled by QSCALE so attention's
// exp2-domain softmax scale is free (q = (QSC*W)x + QSC*b; RoPE commutes with scalars).
__global__ __launch_bounds__(256) void k_convert(const float* __restrict__ s0,
                                                 const float* __restrict__ s1,
                                                 const float* __restrict__ s2,
                                                 unsigned short* __restrict__ dst) {
    int base = blockIdx.x * 256 + threadIdx.x;  // grid 1024 -> 262144 threads
#pragma unroll
    for (int v = 0; v < 4; ++v) {
        int i = base + v * 262144;
        const float* src;
        int rel;
        float sc = 1.0f;
        if (i < 524288) { src = s0; rel = i; }
        else if (i < 917504) {
            src = s1; rel = i - 524288;
            if (rel < 131072) sc = QSCALE;   // q-weight rows
        }
        else { src = s2; rel = i - 917504; }
        const float4* p = (const float4*)src + (size_t)rel * 2;
        float4 a = p[0], bq = p[1];
        u16x8 o;
        o[0] = f2bf(a.x * sc);  o[1] = f2bf(a.y * sc);
        o[2] = f2bf(a.z * sc);  o[3] = f2bf(a.w * sc);
        o[4] = f2bf(bq.x * sc); o[5] = f2bf(bq.y * sc);
        o[6] = f2bf(bq.z * sc); o[7] = f2bf(bq.w * sc);
        *((u16x8*)dst + i) = o;
    }
}

// ---------- RoPE on head 0 of q and k, vectorized: 256x256, 8 elems/thread ----------
__global__ __launch_bounds__(256) void k_rope(unsigned short* __restrict__ qk,
                                              const float* __restrict__ cosp,
                                              const float* __restrict__ sinp) {
    int gid = blockIdx.x * 256 + threadIdx.x;   // grid 256 -> 65536 threads
    int row = gid >> 4;
    int seg = gid & 15;
    int which = seg >> 3;
    int e0 = (seg & 7) * 8;
    unsigned short* base = qk + (size_t)row * 2048 + which * 1024 + e0;
    u16x8 v = *(u16x8*)base;
    const float* cb = cosp + (size_t)row * 64 + e0;
    const float* sb = sinp + (size_t)row * 64 + e0;
    float4 c0 = *(const float4*)cb, c1 = *(const float4*)(cb + 4);
    float4 s0 = *(const float4*)sb, s1 = *(const float4*)(sb + 4);
    float c[8] = {c0.x, c0.y, c0.z, c0.w, c1.x, c1.y, c1.z, c1.w};
    float s[8] = {s0.x, s0.y, s0.z, s0.w, s1.x, s1.y, s1.z, s1.w};
    u16x8 o;
#pragma unroll
    for (int p = 0; p < 4; ++p) {
        float x0 = bf2f(v[2 * p]);
        float x1 = bf2f(v[2 * p + 1]);
        o[2 * p]     = f2bf(x0 * c[2 * p] - x1 * s[2 * p]);
        o[2 * p + 1] = f2bf(x1 * c[2 * p + 1] + x0 * s[2 * p + 1]);
    }
    *(u16x8*)base = o;
}

// ---------- NT GEMM: C[M,N] = A[M,K] * B[N,K]^T + bias ----------
// Round-18 form (measured best): single-buffered LDS for A and B (r10 dbuf and r19
// B-direct-to-reg both regressed — B's K-major layout makes per-lane fragment loads
// uncoalesced 64B segments; gload_lds's 1KB coalesced wave-load is strictly better).
// + T1 XCD-chunked grid swizzle (bijective; chunk grid (NX/CX)*(NY/CY) == 8): each XCD's
// L2 holds a contiguous A-panel x B-panel working set.
// LDS tiles XOR-swizzled (T2, rule 21): linear gload_lds dest, source chunk pre-swizzled
// (tkb = (tid&7)^((tid>>3)&7)), fragment reads XOR col with (lr&7)<<3 (u16 units).
// MODE 0: qkv epilogue -> q,k bf16 into outQK[4096][2048] (q-columns' bias scaled by
// QSCALE to match pre-scaled q-weights); v -> fragment-tiled outVg.
// MODE 1: f32 epilogue -> outF[M][N]
template <int MODE, int BM, int NX, int CX, int CY>
__global__ __launch_bounds__(256) void k_gemm_nt(
    const unsigned short* __restrict__ A, const unsigned short* __restrict__ B,
    const float* __restrict__ bias, unsigned short* __restrict__ outQK,
    unsigned short* __restrict__ outVg, float* __restrict__ outF, int M, int N, int K) {
    constexpr int MI = BM / 32;          // acc rows per wave / 16
    __shared__ __align__(16) unsigned short As[BM * 64];
    __shared__ __align__(16) unsigned short Bs[128 * 64];
    const int tid = threadIdx.x;
    const int w = tid >> 6, l = tid & 63, lr = l & 15, lg = l >> 4;
    const int wm = w >> 1, wn = w & 1;

    // XCD-chunked block swizzle (bijective; chunk grid (NX/CX) x (NY/CY) == 8)
    const int flat = blockIdx.x;
    const int xcd = flat & 7, within = flat >> 3;
    const int bx = (xcd % (NX / CX)) * CX + within % CX;
    const int by = (xcd / (NX / CX)) * CY + within / CX;
    const int m0 = by * BM, n0 = bx * 128;

    f32x4 acc[MI][4];
    f32x4 zero4 = {0.f, 0.f, 0.f, 0.f};
#pragma unroll
    for (int i = 0; i < MI; ++i)
#pragma unroll
        for (int j = 0; j < 4; ++j) acc[i][j] = zero4;

    const int trow = tid >> 3;
    const int tkb = (tid & 7) ^ ((tid >> 3) & 7);   // inverse-swizzled source chunk
    const unsigned short* Ag = A + (size_t)(m0 + trow) * K + tkb * 8;
    const unsigned short* Bg = B + (size_t)(n0 + trow) * K + tkb * 8;
    const int rsw = (lr & 7) << 3;                  // read-side swizzle (u16 units)

    for (int kt = 0; kt < K; kt += 64) {
#pragma unroll
        for (int i = 0; i < BM / 32; ++i)
            gload16(Ag + (size_t)i * 32 * K + kt, (unsigned short*)((char*)As + i * 4096 + w * 1024));
#pragma unroll
        for (int i = 0; i < 4; ++i)
            gload16(Bg + (size_t)i * 32 * K + kt, (unsigned short*)((char*)Bs + i * 4096 + w * 1024));
        asm volatile("s_waitcnt vmcnt(0)" ::: "memory");
        __syncthreads();
        bf16x8 af[MI][2], bfr[4][2];
#pragma unroll
        for (int mi = 0; mi < MI; ++mi)
#pragma unroll
            for (int s = 0; s < 2; ++s)
                af[mi][s] = *(const bf16x8*)&As[(wm * (BM / 2) + mi * 16 + lr) * 64 +
                                                ((s * 32 + lg * 8) ^ rsw)];
#pragma unroll
        for (int ni = 0; ni < 4; ++ni)
#pragma unroll
            for (int s = 0; s < 2; ++s)
                bfr[ni][s] = *(const bf16x8*)&Bs[(wn * 64 + ni * 16 + lr) * 64 +
                                                 ((s * 32 + lg * 8) ^ rsw)];
#pragma unroll
        for (int mi = 0; mi < MI; ++mi)
#pragma unroll
            for (int ni = 0; ni < 4; ++ni)
#pragma unroll
                for (int s = 0; s < 2; ++s)
                    acc[mi][ni] = MFMA16(af[mi][s], bfr[ni][s], acc[mi][ni]);
        __syncthreads();
    }

#pragma unroll
    for (int mi = 0; mi < MI; ++mi)
#pragma unroll
        for (int ni = 0; ni < 4; ++ni) {
            int gc = n0 + wn * 64 + ni * 16 + lr;
            int gr0 = m0 + wm * (BM / 2) + mi * 16 + lg * 4;
            float bv = bias[gc];
            if (MODE == 0 && gc < 1024) bv *= QSCALE;   // match pre-scaled q-weights
            f32x4 v = acc[mi][ni];
            if (MODE == 0) {
                if (gc < 2048) {
#pragma unroll
                    for (int r = 0; r < 4; ++r)
                        outQK[(size_t)(gr0 + r) * 2048 + gc] = f2bf(v[r] + bv);
                } else {
                    // V -> fragment-tiled layout (see k_attn V loads):
                    // addr(u16) = ((bh*32+T)*8 + db*4 + ks)*512 + (hi8*32+lq)*8 + j
                    int e = gc - 2048;
                    int hh = e >> 6, d = e & 63;
                    int bb = gr0 >> 11, s = gr0 & 2047;  // s multiple of 4
                    int bh = bb * NH + hh;
                    int T = s >> 6, w64 = s & 63;
                    int ks = w64 >> 4, hi8 = (w64 >> 3) & 1, j0 = w64 & 7;  // j0 in {0,4}
                    int db = d >> 5, lqv = d & 31;
                    u16x4 pk;
#pragma unroll
                    for (int r = 0; r < 4; ++r) pk[r] = f2bf(v[r] + bv);
                    size_t off = ((size_t)((bh * 32 + T) * 8 + db * 4 + ks)) * 512 +
                                 (hi8 * 32 + lqv) * 8 + j0;
                    *(u16x4*)&outVg[off] = pk;
                }
            } else {
#pragma unroll
                for (int r = 0; r < 4; ++r)
                    outF[(size_t)(gr0 + r) * N + gc] = v[r] + bv;
            }
        }
}

// ---------- flash attention: full-kv per block, software-pipelined (round-14 form) ----------
// grid 1024 (XCD-swizzled), 128 threads = 2 waves, 32 q-rows/wave, 32 kv-tiles.
// Body t: stage K_{t+2} | load V_{t+1} | QK_{t+1} (MFMA) | PV_t + l-MFMA | exp2 | pack
// | vmcnt(8) (drain own K-stage, keep V in flight) | raw s_barrier.
// Row-sum l on the MATRIX pipe: lacc = MFMA32(pa, ones) (C-col of ones-B MFMA = row sum;
// row mapping matches oacc) — no VALU sum chain, no epilogue shuffles.
// Q arrives pre-scaled by QSCALE (folded into convert) -> Q-load is two pure b128 loads.
// [r15: barrier-free 1-wave variant was 53 µs vs this form's 49.5 — structural floor.]
#define ATTN_BODY(T, PA, VA0, VA1, PB, VB0, VB1, DOSTAGE)                                \
  {                                                                                      \
    if (DOSTAGE) stageK((T) & 1, (T) + 2);                                               \
    const unsigned short* vtbN = vgb + (size_t)((T) + 1) * 4096;                         \
    _Pragma("unroll") for (int ks = 0; ks < 4; ++ks)                                     \
        VB0[ks] = *(const bf16x8*)&vtbN[(size_t)ks * 512 + l * 8];                       \
    _Pragma("unroll") for (int ks = 0; ks < 4; ++ks)                                     \
        VB1[ks] = *(const bf16x8*)&vtbN[(size_t)(4 + ks) * 512 + l * 8];                 \
    const char* Kb = (const char*)Ks[((T) + 1) & 1];                                     \
    f32x16 s0, s1;                                                                       \
    __builtin_amdgcn_s_setprio(1);                                                       \
    _Pragma("unroll") for (int ds = 0; ds < 4; ++ds) {                                   \
        bf16x8 kf0 = *(const bf16x8*)(Kb + lq * 128 + ((ds * 32 + hi * 16) ^ swz));      \
        bf16x8 kf1 = *(const bf16x8*)(Kb + (32 + lq) * 128 + ((ds * 32 + hi * 16) ^ swz)); \
        s0 = (ds == 0) ? MFMA32(kf0, qf[0], z16) : MFMA32(kf0, qf[ds], s0);              \
        s1 = (ds == 0) ? MFMA32(kf1, qf[0], z16) : MFMA32(kf1, qf[ds], s1);              \
    }                                                                                    \
    _Pragma("unroll") for (int ks = 0; ks < 4; ++ks) {                                   \
        oacc[0] = MFMA32(PA[ks], VA0[ks], oacc[0]);                                      \
        oacc[1] = MFMA32(PA[ks], VA1[ks], oacc[1]);                                      \
        lacc    = MFMA32(PA[ks], vones,   lacc);                                         \
    }                                                                                    \
    __builtin_amdgcn_s_setprio(0);                                                       \
    _Pragma("unroll") for (int r = 0; r < 16; ++r) {                                     \
        s0[r] = __builtin_amdgcn_exp2f(s0[r]);                                           \
        s1[r] = __builtin_amdgcn_exp2f(s1[r]);                                           \
    }                                                                                    \
    _Pragma("unroll") for (int ks = 0; ks < 4; ++ks) {                                   \
        const int k2 = ks & 1;                                                           \
        f32x16& sb = (ks < 2) ? s0 : s1;                                                 \
        unsigned XA = cvt_pk_bf16(sb[8 * k2 + 0], sb[8 * k2 + 1]);                       \
        unsigned YA = cvt_pk_bf16(sb[8 * k2 + 2], sb[8 * k2 + 3]);                       \
        unsigned XB = cvt_pk_bf16(sb[8 * k2 + 4], sb[8 * k2 + 5]);                       \
        unsigned YB = cvt_pk_bf16(sb[8 * k2 + 6], sb[8 * k2 + 7]);                       \
        asm("v_permlane32_swap_b32 %0, %1" : "+v"(XA), "+v"(XB));                        \
        asm("v_permlane32_swap_b32 %0, %1" : "+v"(YA), "+v"(YB));                        \
        uint32x4 pw;                                                                     \
        pw[0] = XA; pw[1] = YA; pw[2] = XB; pw[3] = YB;                                  \
        PB[ks] = __builtin_bit_cast(bf16x8, pw);                                         \
    }                                                                                    \
    if (DOSTAGE) {                                                                      \
        asm volatile("s_waitcnt vmcnt(8)" ::: "memory");                                 \
        __builtin_amdgcn_s_barrier();                                                    \
    }                                                                                    \
  }

__global__ __launch_bounds__(128, 2) void k_attn(const unsigned short* __restrict__ qk,
                                                 const unsigned short* __restrict__ vg,
                                                 unsigned short* __restrict__ ao) {
    const int raw = blockIdx.x;
    const int bid = (raw & 7) * 128 + (raw >> 3);  // XCD swizzle: 4 bh-groups per XCD
    const int qt = bid & 31, bh = bid >> 5, b = bh >> 4, h = bh & 15;
    const int tid = threadIdx.x, w = tid >> 6, l = tid & 63;
    const int lq = l & 31, hi = l >> 5;

    __shared__ __align__(16) unsigned short Ks[2][4096];  // [kv 64][d 64], XOR-swizzled cols

    const size_t rowbase = (size_t)b * SB;
    const int qrow = qt * 64 + w * 32 + lq;

    // Q B-fragments (pre-scaled in convert): qf[ds] = Q[qrow][16ds + 8hi .. +8)
    bf16x8 qf[4];
#pragma unroll
    for (int ds = 0; ds < 4; ++ds)
        qf[ds] = *(const bf16x8*)&qk[(rowbase + qrow) * 2048 + h * 64 + ds * 16 + hi * 8];

    // ones B-fragment for the l-MFMA (every element 1.0bf16)
    u16x8 onesu;
#pragma unroll
    for (int j = 0; j < 8; ++j) onesu[j] = 0x3F80;
    const bf16x8 vones = __builtin_bit_cast(bf16x8, onesu);

    // K staging: linear LDS dest, inverse-swizzled global source (rule 21)
    const char* ksrc[4];
#pragma unroll
    for (int j = 0; j < 4; ++j) {
        int Lb = (j * 2 + w) * 1024 + l * 16;
        int r = Lb >> 7, c = Lb & 127;
        int cs = c ^ ((r & 7) << 4);
        ksrc[j] = (const char*)qk + ((size_t)(rowbase + r) * 2048 + 1024 + h * 64) * 2 + cs;
    }
    auto stageK = [&](int bufi, int tg) {
#pragma unroll
        for (int j = 0; j < 4; ++j)
            gload16((const unsigned short*)(ksrc[j] + (size_t)tg * 262144),
                    Ks[bufi] + (j * 2 + w) * 512);
    };

    const unsigned short* vgb = vg + (size_t)bh * 131072;  // 32 tiles * 8 frags * 512

    f32x16 z16 = {0.f, 0.f, 0.f, 0.f, 0.f, 0.f, 0.f, 0.f,
                  0.f, 0.f, 0.f, 0.f, 0.f, 0.f, 0.f, 0.f};
    f32x16 oacc[2];
    oacc[0] = z16;
    oacc[1] = z16;
    f32x16 lacc = z16;
    const int swz = (l & 7) << 4;

    bf16x8 vfA0[4], vfA1[4], vfB0[4], vfB1[4];
    bf16x8 paA[4], paB[4];

    // ---- prologue: K_0 staged+drained; K_1 in flight; V_0, QK_0, pack paA ----
    stageK(0, 0);
    __syncthreads();  // full drain: K_0 ready for all waves
    stageK(1, 1);
#pragma unroll
    for (int ks = 0; ks < 4; ++ks)
        vfA0[ks] = *(const bf16x8*)&vgb[(size_t)ks * 512 + l * 8];
#pragma unroll
    for (int ks = 0; ks < 4; ++ks)
        vfA1[ks] = *(const bf16x8*)&vgb[(size_t)(4 + ks) * 512 + l * 8];
    {
        const char* Kb = (const char*)Ks[0];
        f32x16 s0, s1;
#pragma unroll
        for (int ds = 0; ds < 4; ++ds) {
            bf16x8 kf0 = *(const bf16x8*)(Kb + lq * 128 + ((ds * 32 + hi * 16) ^ swz));
            bf16x8 kf1 = *(const bf16x8*)(Kb + (32 + lq) * 128 + ((ds * 32 + hi * 16) ^ swz));
            s0 = (ds == 0) ? MFMA32(kf0, qf[0], z16) : MFMA32(kf0, qf[ds], s0);
            s1 = (ds == 0) ? MFMA32(kf1, qf[0], z16) : MFMA32(kf1, qf[ds], s1);
        }
#pragma unroll
        for (int r = 0; r < 16; ++r) {
            s0[r] = __builtin_amdgcn_exp2f(s0[r]);
            s1[r] = __builtin_amdgcn_exp2f(s1[r]);
        }
#pragma unroll
        for (int ks = 0; ks < 4; ++ks) {
            const int k2 = ks & 1;
            f32x16& sb = (ks < 2) ? s0 : s1;
            unsigned XA = cvt_pk_bf16(sb[8 * k2 + 0], sb[8 * k2 + 1]);
            unsigned YA = cvt_pk_bf16(sb[8 * k2 + 2], sb[8 * k2 + 3]);
            unsigned XB = cvt_pk_bf16(sb[8 * k2 + 4], sb[8 * k2 + 5]);
            unsigned YB = cvt_pk_bf16(sb[8 * k2 + 6], sb[8 * k2 + 7]);
            asm("v_permlane32_swap_b32 %0, %1" : "+v"(XA), "+v"(XB));
            asm("v_permlane32_swap_b32 %0, %1" : "+v"(YA), "+v"(YB));
            uint32x4 pw;
            pw[0] = XA; pw[1] = YA; pw[2] = XB; pw[3] = YB;
            paA[ks] = __builtin_bit_cast(bf16x8, pw);
        }
    }
    asm volatile("s_waitcnt vmcnt(8)" ::: "memory");  // drain K_1 stage; keep V_0 loads
    __builtin_amdgcn_s_barrier();

    // ---- main loop: bodies t = 0..29 paired (A->B, B->A), tail t = 30 ----
    for (int tt = 0; tt < 15; ++tt) {
        const int t = 2 * tt;
        ATTN_BODY(t,     paA, vfA0, vfA1, paB, vfB0, vfB1, true)
        ATTN_BODY(t + 1, paB, vfB0, vfB1, paA, vfA0, vfA1, true)
    }
    ATTN_BODY(30, paA, vfA0, vfA1, paB, vfB0, vfB1, false)
    // tail PV_31 (+ l accumulation)
    __builtin_amdgcn_s_setprio(1);
#pragma unroll
    for (int ks = 0; ks < 4; ++ks) {
        oacc[0] = MFMA32(paB[ks], vfB0[ks], oacc[0]);
        oacc[1] = MFMA32(paB[ks], vfB1[ks], oacc[1]);
        lacc    = MFMA32(paB[ks], vones,   lacc);
    }
    __builtin_amdgcn_s_setprio(0);

    // epilogue: per-lane normalization via lacc (no cross-lane ops)
#pragma unroll
    for (int r = 0; r < 16; ++r) {
        float inv = __builtin_amdgcn_rcpf(lacc[r]);
        int qv = (r & 3) + 8 * (r >> 2) + 4 * hi;
        int qg = qt * 64 + w * 32 + qv;
        ao[(rowbase + qg) * DIMM + h * 64 + lq] = f2bf(oacc[0][r] * inv);
        ao[(rowbase + qg) * DIMM + h * 64 + 32 + lq] = f2bf(oacc[1][r] * inv);
    }
}

// ---------- launch ----------
extern "C" void kernel_launch(void* const* d_in, const int* in_sizes, int n_in,
                              void* d_out, int out_size, void* d_ws, size_t ws_size,
                              hipStream_t stream) {
    const float* hidden = (const float*)d_in[0];
    const float* cosp   = (const float*)d_in[1];
    const float* sinp   = (const float*)d_in[2];
    const float* qkv_w  = (const float*)d_in[3];
    const float* qkv_b  = (const float*)d_in[4];
    const float* out_w  = (const float*)d_in[5];
    const float* out_b  = (const float*)d_in[6];
    float* out = (float*)d_out;

    // ws layout (40 MB):
    unsigned short* hbf   = (unsigned short*)d_ws;                 // [0, 8M)   4M elems
    unsigned short* wqkv  = hbf + (size_t)NROWS * DIMM;            // [8, 14M)  3M elems
    unsigned short* wout  = wqkv + (size_t)3072 * DIMM;            // [14, 16M) 1M elems
    unsigned short* qkbuf = wout + (size_t)DIMM * DIMM;            // [16, 32M) q,k
    unsigned short* vgbuf = qkbuf + (size_t)NROWS * 2048;          // [32, 40M) V fragment-tiled
    unsigned short* aobuf = hbf;                                   // alias: hbf dead after GEMM1

    k_convert<<<1024, 256, 0, stream>>>(hidden, qkv_w, out_w, hbf);
    // GEMM1: NX=24 x NY=32 blocks; XCD chunks 12x8 (2x4 chunk grid = 8 XCDs)
    k_gemm_nt<0, 128, 24, 12, 8><<<768, 256, 0, stream>>>(hbf, wqkv, qkv_b, qkbuf, vgbuf,
                                                          nullptr, NROWS, 3072, DIMM);
    k_rope<<<256, 256, 0, stream>>>(qkbuf, cosp, sinp);
    k_attn<<<1024, 128, 0, stream>>>(qkbuf, vgbuf, aobuf);
    // GEMM2: NX=8 x NY=64 blocks; XCD chunks 8x8 (1x8 chunk grid = 8 XCDs)
    k_gemm_nt<1, 64, 8, 8, 8><<<512, 256, 0, stream>>>(aobuf, wout, out_b, nullptr, nullptr,
                                                       out, NROWS, DIMM, DIMM);
}